// Round 1
// baseline (550.706 us; speedup 1.0000x reference)
//
#include <hip/hip_runtime.h>
#include <hip/hip_bf16.h>
#include <math.h>

#define NTOK 65536
#define DIM  128
#define MKT  32
#define NE   9
#define TOPK 3
#define ALPHA_C 1e-4f

// ws layout (bytes):
//   0    : float mg_acc[32]
//   128  : uint  cnt[9]
//   192  : float gsum[9]
//   256  : float sb[9*128]
//   4864 : int   lists[9*NTOK]
//   4864 + 9*NTOK*4 : float gates[9*NTOK]
static constexpr size_t OFF_MG   = 0;
static constexpr size_t OFF_CNT  = 128;
static constexpr size_t OFF_GSUM = 192;
static constexpr size_t OFF_SB   = 256;
static constexpr size_t OFF_LIST = 4864;
static constexpr size_t OFF_GATE = OFF_LIST + (size_t)NE * NTOK * 4;

// ---------------- K1: market = relu(x@Wr_w + Wr_b); mg_acc[m] += sum_n market*Wl_w[n]
__global__ __launch_bounds__(256) void k_market(const float* __restrict__ x,
    const float* __restrict__ Wrw, const float* __restrict__ Wrb,
    const float* __restrict__ Wlw, float* __restrict__ mg_acc)
{
    __shared__ float xs[64 * 128];   // 32 KB
    __shared__ float wr[128 * 32];   // 16 KB
    __shared__ float part[256][8];   // 8 KB
    int tid = threadIdx.x;
    int base = blockIdx.x * 64;

    const float4* x4 = (const float4*)x + (size_t)base * 32;
    float4* xs4 = (float4*)xs;
    for (int i = tid; i < 64 * 32; i += 256) xs4[i] = x4[i];
    const float4* w4 = (const float4*)Wrw;
    float4* wr4 = (float4*)wr;
    for (int i = tid; i < 128 * 32 / 4; i += 256) wr4[i] = w4[i];
    __syncthreads();

    int tok = tid >> 2, sub = tid & 3, m0 = sub * 8;
    float acc[8];
    #pragma unroll
    for (int k = 0; k < 8; ++k) acc[k] = 0.f;
    for (int d = 0; d < 128; ++d) {
        float xv = xs[tok * 128 + d];
        #pragma unroll
        for (int k = 0; k < 8; ++k) acc[k] += xv * wr[d * 32 + m0 + k];
    }
    float wl = Wlw[base + tok];
    #pragma unroll
    for (int k = 0; k < 8; ++k) {
        float v = acc[k] + Wrb[m0 + k];
        part[tid][k] = (v > 0.f ? v : 0.f) * wl;
    }
    __syncthreads();
    if (tid < 32) {
        int m = tid;
        float s = 0.f;
        for (int t = 0; t < 64; ++t) s += part[t * 4 + (m >> 3)][m & 7];
        atomicAdd(&mg_acc[m], s);
    }
}

// ---------------- K4: style_bias[e][h] = sum_s styles[e][s]*W1[e][128+s][h] + b1[e][h]
__global__ void k_stylebias(const float* __restrict__ styles, const float* __restrict__ W1,
                            const float* __restrict__ b1, float* __restrict__ sb)
{
    int e = blockIdx.x, h = threadIdx.x;
    float acc = b1[e * 128 + h];
    for (int s = 0; s < 32; ++s)
        acc += styles[e * 32 + s] * W1[(size_t)e * 20480 + (size_t)(128 + s) * 128 + h];
    sb[e * 128 + h] = acc;
}

// ---------------- K2: router logits, top-3 softmax, expert lists + fi/Pi stats
__global__ __launch_bounds__(256) void k_router(const float* __restrict__ x,
    const float* __restrict__ rweights, const float* __restrict__ rb,
    const float* __restrict__ mg_acc, const float* __restrict__ Wlb,
    unsigned* __restrict__ cnt, float* __restrict__ gsum,
    int* __restrict__ lists, float* __restrict__ gates)
{
    __shared__ float xs[64 * 128];     // 32 KB
    __shared__ float rw[160 * 9];
    __shared__ float ce[9];
    __shared__ float part[64][4][9];
    __shared__ unsigned lcount[9];
    __shared__ float lgsum[9];
    __shared__ unsigned lbase[9];
    __shared__ int te[64][3];
    __shared__ float tgv[64][3];
    __shared__ unsigned tp[64][3];

    int tid = threadIdx.x;
    int base = blockIdx.x * 64;
    const float4* x4 = (const float4*)x + (size_t)base * 32;
    float4* xs4 = (float4*)xs;
    for (int i = tid; i < 64 * 32; i += 256) xs4[i] = x4[i];
    for (int i = tid; i < 160 * 9; i += 256) rw[i] = rweights[i];
    if (tid < 9) { lcount[tid] = 0u; lgsum[tid] = 0.f; }
    __syncthreads();
    if (tid < 9) {
        float c = rb[tid];
        float wlb = Wlb[0];
        for (int m = 0; m < 32; ++m) c += (mg_acc[m] + wlb) * rw[(128 + m) * 9 + tid];
        ce[tid] = c;
    }
    int tok = tid >> 2, sub = tid & 3;
    float acc[9];
    #pragma unroll
    for (int e = 0; e < 9; ++e) acc[e] = 0.f;
    for (int d = sub * 32; d < sub * 32 + 32; ++d) {
        float xv = xs[tok * 128 + d];
        #pragma unroll
        for (int e = 0; e < 9; ++e) acc[e] += xv * rw[d * 9 + e];
    }
    #pragma unroll
    for (int e = 0; e < 9; ++e) part[tok][sub][e] = acc[e];
    __syncthreads();

    if (sub == 0) {
        float lg[9];
        #pragma unroll
        for (int e = 0; e < 9; ++e)
            lg[e] = ce[e] + part[tok][0][e] + part[tok][1][e] + part[tok][2][e] + part[tok][3][e];
        int used = 0;
        int bi[3]; float bv[3];
        for (int k = 0; k < 3; ++k) {
            float best = -1e30f; int b = -1;
            for (int e = 0; e < 9; ++e)
                if (!((used >> e) & 1) && lg[e] > best) { best = lg[e]; b = e; }
            bi[k] = b; bv[k] = best; used |= 1 << b;
        }
        float p[3]; float s = 0.f;
        for (int k = 0; k < 3; ++k) { p[k] = expf(bv[k] - bv[0]); s += p[k]; }
        for (int k = 0; k < 3; ++k) {
            float g = p[k] / s;
            unsigned pos = atomicAdd(&lcount[bi[k]], 1u);
            te[tok][k] = bi[k]; tgv[tok][k] = g; tp[tok][k] = pos;
            atomicAdd(&lgsum[bi[k]], g);
        }
    }
    __syncthreads();
    if (tid < 9) {
        lbase[tid] = atomicAdd(&cnt[tid], lcount[tid]);
        atomicAdd(&gsum[tid], lgsum[tid]);
    }
    __syncthreads();
    if (sub == 0) {
        for (int k = 0; k < 3; ++k) {
            int e = te[tok][k];
            unsigned idx = lbase[e] + tp[tok][k];
            lists[(size_t)e * NTOK + idx] = base + tok;
            gates[(size_t)e * NTOK + idx] = tgv[tok][k];
        }
    }
}

// ---------------- K3: aux loss scalar
__global__ void k_aux(const unsigned* __restrict__ cnt, const float* __restrict__ gsum,
                      float* __restrict__ out)
{
    float a = 0.f;
    for (int e = 0; e < 9; ++e) {
        float fi = (float)cnt[e] * ((float)NE / ((float)TOPK * (float)NTOK));
        float Pi = gsum[e] / (float)NTOK;
        a += fi * Pi;
    }
    out[(size_t)NTOK * DIM] = ALPHA_C * a;
}

// ---------------- K5: grouped expert FFN. 64 tokens x 128 cols per block.
__global__ __launch_bounds__(256) void k_expert(const float* __restrict__ x,
    const float* __restrict__ W1, const float* __restrict__ W2,
    const float* __restrict__ b2, const float* __restrict__ sb,
    const unsigned* __restrict__ cnt, const int* __restrict__ lists,
    const float* __restrict__ gates, float* __restrict__ out)
{
    int e = blockIdx.y;
    unsigned c = cnt[e];
    unsigned base = blockIdx.x * 64u;
    if (base >= c) return;
    int nt = (int)min(64u, c - base);

    __shared__ float xs[64 * 128];   // 32 KB, reused as H after phase 1
    __shared__ int stok[64];
    __shared__ float sg[64];
    int tid = threadIdx.x;
    if (tid < 64) {
        bool v = tid < nt;
        stok[tid] = v ? lists[(size_t)e * NTOK + base + tid] : 0;
        sg[tid]   = v ? gates[(size_t)e * NTOK + base + tid] : 0.f;
    }
    __syncthreads();

    float4* xs4 = (float4*)xs;
    const float4* x4 = (const float4*)x;
    for (int i = tid; i < 64 * 32; i += 256) {
        int row = i >> 5, c4 = i & 31;
        float4 z = {0.f, 0.f, 0.f, 0.f};
        xs4[i] = (row < nt) ? x4[(size_t)stok[row] * 32 + c4] : z;
    }
    __syncthreads();

    int tg_ = tid >> 5;          // token group: rows tg_*8 .. tg_*8+7
    int c0 = (tid & 31) * 4;     // output cols c0..c0+3
    const float* W1e = W1 + (size_t)e * 20480;  // [160][128], first 128 rows = W1x
    const float* W2e = W2 + (size_t)e * 16384;  // [128][128]

    float acc[8][4];
    #pragma unroll
    for (int t = 0; t < 8; ++t)
        #pragma unroll
        for (int cc = 0; cc < 4; ++cc) acc[t][cc] = 0.f;

    // Phase 1: H = relu(X @ W1x + sb)
    for (int d4 = 0; d4 < 32; ++d4) {
        float w[4][4];
        #pragma unroll
        for (int dd = 0; dd < 4; ++dd) {
            float4 t4 = *(const float4*)(W1e + (size_t)(d4 * 4 + dd) * 128 + c0);
            w[dd][0] = t4.x; w[dd][1] = t4.y; w[dd][2] = t4.z; w[dd][3] = t4.w;
        }
        #pragma unroll
        for (int t = 0; t < 8; ++t) {
            float4 xv = xs4[(tg_ * 8 + t) * 32 + d4];
            #pragma unroll
            for (int cc = 0; cc < 4; ++cc)
                acc[t][cc] += xv.x * w[0][cc] + xv.y * w[1][cc] + xv.z * w[2][cc] + xv.w * w[3][cc];
        }
    }
    __syncthreads();   // all xs reads done; reuse xs as H
    float4 sbv = *(const float4*)(sb + e * 128 + c0);
    #pragma unroll
    for (int t = 0; t < 8; ++t) {
        int row = tg_ * 8 + t;
        float h0 = acc[t][0] + sbv.x, h1 = acc[t][1] + sbv.y,
              h2 = acc[t][2] + sbv.z, h3 = acc[t][3] + sbv.w;
        xs[row * 128 + c0 + 0] = h0 > 0.f ? h0 : 0.f;
        xs[row * 128 + c0 + 1] = h1 > 0.f ? h1 : 0.f;
        xs[row * 128 + c0 + 2] = h2 > 0.f ? h2 : 0.f;
        xs[row * 128 + c0 + 3] = h3 > 0.f ? h3 : 0.f;
    }
    __syncthreads();

    // Phase 2: O = H @ W2; out[token] += g*(O + b2)
    #pragma unroll
    for (int t = 0; t < 8; ++t)
        #pragma unroll
        for (int cc = 0; cc < 4; ++cc) acc[t][cc] = 0.f;
    for (int j4 = 0; j4 < 32; ++j4) {
        float w[4][4];
        #pragma unroll
        for (int dd = 0; dd < 4; ++dd) {
            float4 t4 = *(const float4*)(W2e + (size_t)(j4 * 4 + dd) * 128 + c0);
            w[dd][0] = t4.x; w[dd][1] = t4.y; w[dd][2] = t4.z; w[dd][3] = t4.w;
        }
        #pragma unroll
        for (int t = 0; t < 8; ++t) {
            float4 hv = xs4[(tg_ * 8 + t) * 32 + j4];
            #pragma unroll
            for (int cc = 0; cc < 4; ++cc)
                acc[t][cc] += hv.x * w[0][cc] + hv.y * w[1][cc] + hv.z * w[2][cc] + hv.w * w[3][cc];
        }
    }
    float4 b2v = *(const float4*)(b2 + e * 128 + c0);
    #pragma unroll
    for (int t = 0; t < 8; ++t) {
        int row = tg_ * 8 + t;
        if (row < nt) {
            float g = sg[row];
            size_t o = (size_t)stok[row] * 128 + c0;
            atomicAdd(&out[o + 0], g * (acc[t][0] + b2v.x));
            atomicAdd(&out[o + 1], g * (acc[t][1] + b2v.y));
            atomicAdd(&out[o + 2], g * (acc[t][2] + b2v.z));
            atomicAdd(&out[o + 3], g * (acc[t][3] + b2v.w));
        }
    }
}

extern "C" void kernel_launch(void* const* d_in, const int* in_sizes, int n_in,
                              void* d_out, int out_size, void* d_ws, size_t ws_size,
                              hipStream_t stream) {
    const float* x      = (const float*)d_in[0];
    const float* Wrw    = (const float*)d_in[1];
    const float* Wrb    = (const float*)d_in[2];
    const float* Wlw    = (const float*)d_in[3];
    const float* Wlb    = (const float*)d_in[4];
    const float* rw     = (const float*)d_in[5];
    const float* rb     = (const float*)d_in[6];
    const float* styles = (const float*)d_in[7];
    const float* W1     = (const float*)d_in[8];
    const float* b1     = (const float*)d_in[9];
    const float* W2     = (const float*)d_in[10];
    const float* b2     = (const float*)d_in[11];
    float* out = (float*)d_out;

    char* ws = (char*)d_ws;
    float*    mg    = (float*)(ws + OFF_MG);
    unsigned* cnt   = (unsigned*)(ws + OFF_CNT);
    float*    gsum  = (float*)(ws + OFF_GSUM);
    float*    sb    = (float*)(ws + OFF_SB);
    int*      lists = (int*)(ws + OFF_LIST);
    float*    gates = (float*)(ws + OFF_GATE);

    hipMemsetAsync(ws, 0, 256, stream);                         // mg, cnt, gsum
    hipMemsetAsync(d_out, 0, (size_t)out_size * 4, stream);     // out accumulators

    k_market<<<1024, 256, 0, stream>>>(x, Wrw, Wrb, Wlw, mg);
    k_stylebias<<<9, 128, 0, stream>>>(styles, W1, b1, sb);
    k_router<<<1024, 256, 0, stream>>>(x, rw, rb, mg, Wlb, cnt, gsum, lists, gates);
    k_aux<<<1, 1, 0, stream>>>(cnt, gsum, out);
    k_expert<<<dim3(1024, 9), 256, 0, stream>>>(x, W1, W2, b2, sb, cnt, lists, gates, out);
}

// Round 2
// 390.388 us; speedup vs baseline: 1.4107x; 1.4107x over previous
//
#include <hip/hip_runtime.h>
#include <hip/hip_bf16.h>
#include <math.h>

#define NTOK 65536
#define DIM  128
#define NE   9
#define TOPK 3
#define ALPHA_C 1e-4f

using bf16x8 = __attribute__((ext_vector_type(8))) short;
using f32x4  = __attribute__((ext_vector_type(4))) float;

// ws layout (bytes)
static constexpr size_t OFF_MG   = 0;        // 32 f32
static constexpr size_t OFF_CNT  = 128;      // 27 u32 (expert*3+rank)
static constexpr size_t OFF_GSUM = 256;      // 9 f32
static constexpr size_t OFF_SB   = 320;      // 9*128 f32 -> ends 4928
static constexpr size_t OFF_W1T  = 4928;     // 9*128*128 bf16 = 294912 -> 299840
static constexpr size_t OFF_W2T  = 299840;   // -> 594752
static constexpr size_t OFF_LIST = 594752;   // 27*NTOK*4 = 7077888 -> 7672640
static constexpr size_t OFF_GATE = 7672640;  // 27*NTOK*4 -> 14750528

__device__ __forceinline__ unsigned short f2bf(float f) {
    __hip_bfloat16 h = __float2bfloat16(f);
    return *reinterpret_cast<unsigned short*>(&h);
}

// ---------------- K1: market = relu(x@Wr_w + Wr_b); mg[m] = sum_n market[n][m]*Wl_w[n]
__global__ __launch_bounds__(256) void k_market(const float* __restrict__ x,
    const float* __restrict__ Wrw, const float* __restrict__ Wrb,
    const float* __restrict__ Wlw, float* __restrict__ mg_acc)
{
    __shared__ float xs[64 * 128];
    __shared__ float wr[128 * 32];
    __shared__ float part[256][8];
    int tid = threadIdx.x;
    int base = blockIdx.x * 64;

    const float4* x4 = (const float4*)x + (size_t)base * 32;
    float4* xs4 = (float4*)xs;
    for (int i = tid; i < 64 * 32; i += 256) xs4[i] = x4[i];
    const float4* w4 = (const float4*)Wrw;
    float4* wr4 = (float4*)wr;
    for (int i = tid; i < 128 * 32 / 4; i += 256) wr4[i] = w4[i];
    __syncthreads();

    int tok = tid >> 2, sub = tid & 3, m0 = sub * 8;
    float acc[8];
    #pragma unroll
    for (int k = 0; k < 8; ++k) acc[k] = 0.f;
    for (int d = 0; d < 128; ++d) {
        float xv = xs[tok * 128 + d];
        #pragma unroll
        for (int k = 0; k < 8; ++k) acc[k] += xv * wr[d * 32 + m0 + k];
    }
    float wl = Wlw[base + tok];
    #pragma unroll
    for (int k = 0; k < 8; ++k) {
        float v = acc[k] + Wrb[m0 + k];
        part[tid][k] = (v > 0.f ? v : 0.f) * wl;
    }
    __syncthreads();
    if (tid < 32) {
        int m = tid;
        float s = 0.f;
        for (int t = 0; t < 64; ++t) s += part[t * 4 + (m >> 3)][m & 7];
        atomicAdd(&mg_acc[m], s);
    }
}

// ---------------- K_prepw: W1x, W2 -> bf16 transposed [n][k] per expert
__global__ __launch_bounds__(256) void k_prepw(const float* __restrict__ W1,
    const float* __restrict__ W2, unsigned short* __restrict__ W1T,
    unsigned short* __restrict__ W2T)
{
    __shared__ float t1[32][129];
    __shared__ float t2[32][129];
    int e = blockIdx.x;
    int tid = threadIdx.x;
    const float* W1e = W1 + (size_t)e * 20480;   // [160][128], first 128 rows
    const float* W2e = W2 + (size_t)e * 16384;   // [128][128]
    unsigned short* o1 = W1T + (size_t)e * 16384;
    unsigned short* o2 = W2T + (size_t)e * 16384;
    for (int kb = 0; kb < 128; kb += 32) {
        __syncthreads();
        for (int i = tid; i < 32 * 128; i += 256) {
            int k = i >> 7, n = i & 127;
            t1[k][n] = W1e[(size_t)(kb + k) * 128 + n];
            t2[k][n] = W2e[(size_t)(kb + k) * 128 + n];
        }
        __syncthreads();
        for (int i = tid; i < 128 * 32; i += 256) {
            int n = i >> 5, kk = i & 31;
            o1[(size_t)n * 128 + kb + kk] = f2bf(t1[kk][n]);
            o2[(size_t)n * 128 + kb + kk] = f2bf(t2[kk][n]);
        }
    }
}

// ---------------- K4: style_bias[e][h]
__global__ void k_stylebias(const float* __restrict__ styles, const float* __restrict__ W1,
                            const float* __restrict__ b1, float* __restrict__ sb)
{
    int e = blockIdx.x, h = threadIdx.x;
    float acc = b1[e * 128 + h];
    for (int s = 0; s < 32; ++s)
        acc += styles[e * 32 + s] * W1[(size_t)e * 20480 + (size_t)(128 + s) * 128 + h];
    sb[e * 128 + h] = acc;
}

// ---------------- K2: router logits, top-3 softmax, (expert,rank) lists + stats
__global__ __launch_bounds__(256) void k_router(const float* __restrict__ x,
    const float* __restrict__ rweights, const float* __restrict__ rb,
    const float* __restrict__ mg_acc, const float* __restrict__ Wlb,
    unsigned* __restrict__ cnt, float* __restrict__ gsum,
    int* __restrict__ lists, float* __restrict__ gates)
{
    __shared__ float xs[64 * 128];
    __shared__ float rw[160 * 9];
    __shared__ float ce[9];
    __shared__ float part[64][4][9];
    __shared__ unsigned lcount[27];
    __shared__ float lgsum[9];
    __shared__ unsigned lbase[27];
    __shared__ int te[64][3];
    __shared__ float tgv[64][3];
    __shared__ unsigned tp[64][3];

    int tid = threadIdx.x;
    int base = blockIdx.x * 64;
    const float4* x4 = (const float4*)x + (size_t)base * 32;
    float4* xs4 = (float4*)xs;
    for (int i = tid; i < 64 * 32; i += 256) xs4[i] = x4[i];
    for (int i = tid; i < 160 * 9; i += 256) rw[i] = rweights[i];
    if (tid < 27) lcount[tid] = 0u;
    if (tid < 9) lgsum[tid] = 0.f;
    __syncthreads();
    if (tid < 9) {
        float c = rb[tid];
        float wlb = Wlb[0];
        for (int m = 0; m < 32; ++m) c += (mg_acc[m] + wlb) * rw[(128 + m) * 9 + tid];
        ce[tid] = c;
    }
    int tok = tid >> 2, sub = tid & 3;
    float acc[9];
    #pragma unroll
    for (int e = 0; e < 9; ++e) acc[e] = 0.f;
    for (int d = sub * 32; d < sub * 32 + 32; ++d) {
        float xv = xs[tok * 128 + d];
        #pragma unroll
        for (int e = 0; e < 9; ++e) acc[e] += xv * rw[d * 9 + e];
    }
    #pragma unroll
    for (int e = 0; e < 9; ++e) part[tok][sub][e] = acc[e];
    __syncthreads();

    if (sub == 0) {
        float lg[9];
        #pragma unroll
        for (int e = 0; e < 9; ++e)
            lg[e] = ce[e] + part[tok][0][e] + part[tok][1][e] + part[tok][2][e] + part[tok][3][e];
        int used = 0;
        int bi[3]; float bv[3];
        for (int k = 0; k < 3; ++k) {
            float best = -1e30f; int b = -1;
            for (int e = 0; e < 9; ++e)
                if (!((used >> e) & 1) && lg[e] > best) { best = lg[e]; b = e; }
            bi[k] = b; bv[k] = best; used |= 1 << b;
        }
        float p[3]; float s = 0.f;
        for (int k = 0; k < 3; ++k) { p[k] = expf(bv[k] - bv[0]); s += p[k]; }
        for (int k = 0; k < 3; ++k) {
            float g = p[k] / s;
            unsigned pos = atomicAdd(&lcount[bi[k] * 3 + k], 1u);
            te[tok][k] = bi[k]; tgv[tok][k] = g; tp[tok][k] = pos;
            atomicAdd(&lgsum[bi[k]], g);
        }
    }
    __syncthreads();
    if (tid < 27) lbase[tid] = atomicAdd(&cnt[tid], lcount[tid]);
    if (tid < 9)  atomicAdd(&gsum[tid], lgsum[tid]);
    __syncthreads();
    if (sub == 0) {
        for (int k = 0; k < 3; ++k) {
            int li = te[tok][k] * 3 + k;
            unsigned idx = lbase[li] + tp[tok][k];
            lists[(size_t)li * NTOK + idx] = base + tok;
            gates[(size_t)li * NTOK + idx] = tgv[tok][k];
        }
    }
}

// ---------------- K3: aux loss scalar
__global__ void k_aux(const unsigned* __restrict__ cnt, const float* __restrict__ gsum,
                      float* __restrict__ out)
{
    float a = 0.f;
    for (int e = 0; e < 9; ++e) {
        unsigned ce = cnt[e * 3] + cnt[e * 3 + 1] + cnt[e * 3 + 2];
        float fi = (float)ce * ((float)NE / ((float)TOPK * (float)NTOK));
        float Pi = gsum[e] / (float)NTOK;
        a += fi * Pi;
    }
    out[(size_t)NTOK * DIM] = ALPHA_C * a;
}

// ---------------- K5: grouped expert FFN, MFMA bf16. One (expert,rank) list per pass;
// within a rank every token appears once -> no atomics (rank0 stores, rank>0 adds).
__global__ __launch_bounds__(256) void k_expert(const float* __restrict__ x,
    const unsigned short* __restrict__ W1T, const unsigned short* __restrict__ W2T,
    const float* __restrict__ b2, const float* __restrict__ sb,
    const unsigned* __restrict__ cnt, const int* __restrict__ lists,
    const float* __restrict__ gates, float* __restrict__ out, int rank)
{
    int e = blockIdx.y;
    unsigned c = cnt[e * 3 + rank];
    unsigned base = blockIdx.x * 64u;
    if (base >= c) return;
    int nt = (int)min(64u, c - base);

    __shared__ unsigned short xs[64 * 128];   // 16 KB, XOR-swizzled bf16
    __shared__ unsigned short hs[64 * 128];   // 16 KB
    __shared__ int stok[64];
    __shared__ float sg[64];

    int tid = threadIdx.x;
    int li = e * 3 + rank;
    if (tid < 64) {
        bool v = tid < nt;
        stok[tid] = v ? lists[(size_t)li * NTOK + base + tid] : 0;
        sg[tid]   = v ? gates[(size_t)li * NTOK + base + tid] : 0.f;
    }
    __syncthreads();

    // stage X rows (gathered), f32 -> bf16, swizzle 16B chunks: chunk ^= (row&7)
    const float4* x4 = (const float4*)x;
    for (int i = tid; i < 64 * 32; i += 256) {
        int row = i >> 5, p = i & 31;               // p = 8-byte piece (4 bf16)
        float4 v;
        if (row < nt) v = x4[(size_t)stok[row] * 32 + p];
        else { v.x = 0.f; v.y = 0.f; v.z = 0.f; v.w = 0.f; }
        unsigned short u[4] = { f2bf(v.x), f2bf(v.y), f2bf(v.z), f2bf(v.w) };
        int sw = ((((p >> 1) ^ (row & 7)) << 4) | ((p & 1) << 3));
        *(ushort4*)((char*)xs + row * 256 + sw) = *(ushort4*)u;
    }
    __syncthreads();

    int lane = tid & 63, w = tid >> 6;
    int cb = lane & 15;       // C col offset within 16-tile / A row offset
    int kq = lane >> 4;       // K quarter
    int arow = w * 16 + cb;

    const unsigned short* W1e = W1T + (size_t)e * 16384;
    const unsigned short* W2e = W2T + (size_t)e * 16384;

    f32x4 acc[8];
    #pragma unroll
    for (int n = 0; n < 8; ++n) acc[n] = (f32x4){0.f, 0.f, 0.f, 0.f};

    // Phase 1: H = relu(X @ W1x + sb)
    #pragma unroll
    for (int kk = 0; kk < 4; ++kk) {
        bf16x8 a = *(const bf16x8*)((const char*)xs + arow * 256 + ((((kk * 4 + kq) ^ (arow & 7)) << 4)));
        #pragma unroll
        for (int n = 0; n < 8; ++n) {
            bf16x8 b = *(const bf16x8*)(W1e + (size_t)(n * 16 + cb) * 128 + kk * 32 + kq * 8);
            acc[n] = __builtin_amdgcn_mfma_f32_16x16x32_bf16(a, b, acc[n], 0, 0, 0);
        }
    }
    #pragma unroll
    for (int n = 0; n < 8; ++n) {
        int col = n * 16 + cb;
        float sbv = sb[e * 128 + col];
        #pragma unroll
        for (int r = 0; r < 4; ++r) {
            int row = w * 16 + kq * 4 + r;
            float h = acc[n][r] + sbv;
            h = h > 0.f ? h : 0.f;
            int byte = col * 2;
            int sw = ((((byte >> 4) ^ (row & 7)) << 4) | (byte & 15));
            *(unsigned short*)((char*)hs + row * 256 + sw) = f2bf(h);
        }
    }
    __syncthreads();

    // Phase 2: O = H @ W2
    #pragma unroll
    for (int n = 0; n < 8; ++n) acc[n] = (f32x4){0.f, 0.f, 0.f, 0.f};
    #pragma unroll
    for (int kk = 0; kk < 4; ++kk) {
        bf16x8 a = *(const bf16x8*)((const char*)hs + arow * 256 + ((((kk * 4 + kq) ^ (arow & 7)) << 4)));
        #pragma unroll
        for (int n = 0; n < 8; ++n) {
            bf16x8 b = *(const bf16x8*)(W2e + (size_t)(n * 16 + cb) * 128 + kk * 32 + kq * 8);
            acc[n] = __builtin_amdgcn_mfma_f32_16x16x32_bf16(a, b, acc[n], 0, 0, 0);
        }
    }
    #pragma unroll
    for (int n = 0; n < 8; ++n) {
        int col = n * 16 + cb;
        float b2v = b2[e * 128 + col];
        #pragma unroll
        for (int r = 0; r < 4; ++r) {
            int row = w * 16 + kq * 4 + r;
            if (row < nt) {
                float v = sg[row] * (acc[n][r] + b2v);
                float* op = out + (size_t)stok[row] * 128 + col;
                if (rank == 0) *op = v;
                else          *op += v;
            }
        }
    }
}

extern "C" void kernel_launch(void* const* d_in, const int* in_sizes, int n_in,
                              void* d_out, int out_size, void* d_ws, size_t ws_size,
                              hipStream_t stream) {
    const float* x      = (const float*)d_in[0];
    const float* Wrw    = (const float*)d_in[1];
    const float* Wrb    = (const float*)d_in[2];
    const float* Wlw    = (const float*)d_in[3];
    const float* Wlb    = (const float*)d_in[4];
    const float* rw     = (const float*)d_in[5];
    const float* rb     = (const float*)d_in[6];
    const float* styles = (const float*)d_in[7];
    const float* W1     = (const float*)d_in[8];
    const float* b1     = (const float*)d_in[9];
    const float* W2     = (const float*)d_in[10];
    const float* b2     = (const float*)d_in[11];
    float* out = (float*)d_out;

    char* ws = (char*)d_ws;
    float*          mg    = (float*)(ws + OFF_MG);
    unsigned*       cnt   = (unsigned*)(ws + OFF_CNT);
    float*          gsum  = (float*)(ws + OFF_GSUM);
    float*          sbp   = (float*)(ws + OFF_SB);
    unsigned short* W1T   = (unsigned short*)(ws + OFF_W1T);
    unsigned short* W2T   = (unsigned short*)(ws + OFF_W2T);
    int*            lists = (int*)(ws + OFF_LIST);
    float*          gates = (float*)(ws + OFF_GATE);

    hipMemsetAsync(ws, 0, 320, stream);   // mg, cnt, gsum

    k_market<<<1024, 256, 0, stream>>>(x, Wrw, Wrb, Wlw, mg);
    k_prepw<<<9, 256, 0, stream>>>(W1, W2, W1T, W2T);
    k_stylebias<<<9, 128, 0, stream>>>(styles, W1, b1, sbp);
    k_router<<<1024, 256, 0, stream>>>(x, rw, rb, mg, Wlb, cnt, gsum, lists, gates);
    k_aux<<<1, 1, 0, stream>>>(cnt, gsum, out);
    for (int r = 0; r < 3; ++r)
        k_expert<<<dim3(1024, 9), 256, 0, stream>>>(x, W1T, W2T, b2, sbp, cnt, lists, gates, out, r);
}